// Round 13
// baseline (299.091 us; speedup 1.0000x reference)
//
#include <hip/hip_runtime.h>
#include <math.h>

// Problem constants (fixed by the reference): N=8, B=4096, D=1024.
#define NN 8
#define BB 4096
#define DD 1024
#define LOG_2PI 1.8378770664093453f

// R11: explicit counted-vmcnt pipeline (T4 at register level).
// R5..R10 all land at 110-130 us regardless of structure: per-wave lifetime
// ~19 us for ~3 us of work -> the depth-2 register pipeline never overlaps.
// Compiler-inserted waitcnt (conservative vmcnt(0) per step) serializes the
// 7 scan steps into 7 congested round-trips. R8's spill traffic accidentally
// proved the fabric sustains 2.9 TB/s with a deep request queue.
// R11: quarter-row per wave (4 elems/lane). ALL 16 plane loads issued as
// volatile inline-asm global_load_dwordx4 (issue order = program order),
// then counted s_waitcnt vmcnt(14..0) before each scan step. Ordering is
// enforced by DATA DEPENDENCE: each waitcnt asm ties its two guarded buffers
// as "+v" operands, so compute cannot be hoisted above the wait (rule-18-safe
// without sched_barrier). ~90 VGPR, no launch_bounds cap (R8/R9 spill lesson).

typedef float f32x4 __attribute__((ext_vector_type(4)));

#define GLD(dst, sp) \
    asm volatile("global_load_dwordx4 %0, %1, %2" : "=v"(dst) : "v"(voff), "s"(sp))

#define VWAIT(imm, a, b) \
    asm volatile("s_waitcnt vmcnt(" #imm ")" : "+v"(a), "+v"(b))

#define STEP(Mn, Ln)                                            \
    do {                                                        \
        _Pragma("unroll")                                       \
        for (int j = 0; j < 4; ++j) {                           \
            float mj  = Mn[j];                                  \
            float lj  = Ln[j];                                  \
            float v2  = __expf(lj);                             \
            float iv2 = __expf(-lj);                            \
            float v1e = __builtin_amdgcn_rcpf(iv1[j]);          \
            float s   = v1e + v2 + 1e-6f;                       \
            float d   = m1[j] - mj;                             \
            z += d * d * __builtin_amdgcn_rcpf(s) + __logf(s);  \
            float ivn = iv1[j] + iv2;                           \
            float cv  = __builtin_amdgcn_rcpf(ivn);             \
            m1[j]  = cv * (m1[j] * iv1[j] + mj * iv2);          \
            iv1[j] = ivn;                                       \
        }                                                       \
    } while (0)

__global__ __launch_bounds__(256) void mpc_kernel(
    const float* __restrict__ means,
    const float* __restrict__ logsig,
    float* __restrict__ out_mean,
    float* __restrict__ out_logvar,
    float* __restrict__ out_logz)
{
    const int t    = threadIdx.x;
    const int wave = t >> 6;
    const int lane = t & 63;
    const int row  = blockIdx.x;                    // one row per block
    const size_t plane = (size_t)BB * DD;
    // byte offset within a plane: row*4096 + wave*1024 + lane*16
    const unsigned voff = ((unsigned)row << 12) + ((unsigned)wave << 10)
                        + ((unsigned)lane << 4);
    // element offset for outputs
    const int eoff = (row << 10) + (wave << 8) + (lane << 2);

    const float* a0 = means;              const float* b0 = logsig;
    const float* a1 = means + 1 * plane;  const float* b1 = logsig + 1 * plane;
    const float* a2 = means + 2 * plane;  const float* b2 = logsig + 2 * plane;
    const float* a3 = means + 3 * plane;  const float* b3 = logsig + 3 * plane;
    const float* a4 = means + 4 * plane;  const float* b4 = logsig + 4 * plane;
    const float* a5 = means + 5 * plane;  const float* b5 = logsig + 5 * plane;
    const float* a6 = means + 6 * plane;  const float* b6 = logsig + 6 * plane;
    const float* a7 = means + 7 * plane;  const float* b7 = logsig + 7 * plane;

    // ---- issue ALL 16 loads (volatile asm -> issue order = program order) ----
    f32x4 M0, M1, M2, M3, M4, M5, M6, M7;
    f32x4 L0, L1, L2, L3, L4, L5, L6, L7;
    GLD(M0, a0); GLD(L0, b0);
    GLD(M1, a1); GLD(L1, b1);
    GLD(M2, a2); GLD(L2, b2);
    GLD(M3, a3); GLD(L3, b3);
    GLD(M4, a4); GLD(L4, b4);
    GLD(M5, a5); GLD(L5, b5);
    GLD(M6, a6); GLD(L6, b6);
    GLD(M7, a7); GLD(L7, b7);

    // ---- scan with counted waits: step n waits only for its own plane ----
    float m1[4], iv1[4];
    float z = 0.0f;

    VWAIT(14, M0, L0);
#pragma unroll
    for (int j = 0; j < 4; ++j) {
        m1[j]  = M0[j];
        iv1[j] = __expf(-L0[j]);
    }
    VWAIT(12, M1, L1); STEP(M1, L1);
    VWAIT(10, M2, L2); STEP(M2, L2);
    VWAIT(8,  M3, L3); STEP(M3, L3);
    VWAIT(6,  M4, L4); STEP(M4, L4);
    VWAIT(4,  M5, L5); STEP(M5, L5);
    VWAIT(2,  M6, L6); STEP(M6, L6);
    VWAIT(0,  M7, L7); STEP(M7, L7);

    // ---- outputs (nontemporal; logvar = -log(iv1)) ----
    f32x4 om = {m1[0], m1[1], m1[2], m1[3]};
    f32x4 ol = {-__logf(iv1[0]), -__logf(iv1[1]),
                -__logf(iv1[2]), -__logf(iv1[3])};
    __builtin_nontemporal_store(om, (f32x4*)(out_mean   + eoff));
    __builtin_nontemporal_store(ol, (f32x4*)(out_logvar + eoff));

    // ---- z reduction: wave shuffle, then 4-wave LDS combine ----
#pragma unroll
    for (int o = 32; o > 0; o >>= 1)
        z += __shfl_down(z, o, 64);

    __shared__ float sz[4];
    if (lane == 0) sz[wave] = z;
    __syncthreads();
    if (t == 0) {
        float total = sz[0] + sz[1] + sz[2] + sz[3];
        out_logz[row] = -0.5f * (total + (float)((NN - 1) * DD) * LOG_2PI);
    }
}

extern "C" void kernel_launch(void* const* d_in, const int* in_sizes, int n_in,
                              void* d_out, int out_size, void* d_ws, size_t ws_size,
                              hipStream_t stream) {
    const float* means  = (const float*)d_in[0];
    const float* logsig = (const float*)d_in[1];
    float* out = (float*)d_out;
    float* out_mean   = out;
    float* out_logvar = out + (size_t)BB * DD;
    float* out_logz   = out + 2 * (size_t)BB * DD;
    mpc_kernel<<<BB, 256, 0, stream>>>(means, logsig, out_mean, out_logvar, out_logz);
}

// Round 15
// 295.931 us; speedup vs baseline: 1.0107x; 1.0107x over previous
//
#include <hip/hip_runtime.h>
#include <math.h>

// Problem constants (fixed by the reference): N=8, B=4096, D=1024.
#define NN 8
#define BB 4096
#define DD 1024
#define LOG_2PI 1.8378770664093453f

// R12 (resubmit -- bench never ran, GPU at capacity):
// ONE ELEMENT PER THREAD -- narrow state, full-depth MLP, max TLP.
// R6/R7b/R8/R9/R11 post-mortems: every wide-per-thread pipeline (float4 x 8
// planes = 64+ VGPRs of load dests) is dismantled by the allocator: it either
// shallows the pipeline (R6: VGPR52), balloons to 192 VGPR killing occupancy
// (R7b), or spills (R8/R9/R11). With 1 element/thread the 16 load results are
// 16 SCALAR VGPRs; whole kernel ~36-48 VGPR -> full 16-deep MLP survives
// regalloc trivially AND 8 waves/SIMD = 32 waves/CU (max residency).
// Outstanding: 32 waves x 16 loads x 256 B = 128 KB/CU sustained.
// Scalar dword loads are fully coalesced (64 lanes x 4 B contiguous).
// Block = 1024 threads = one row -> z-reduction stays in-block.

__global__ __launch_bounds__(1024) void mpc_kernel(
    const float* __restrict__ means,
    const float* __restrict__ logsig,
    float* __restrict__ out_mean,
    float* __restrict__ out_logvar,
    float* __restrict__ out_logz)
{
    const int t    = threadIdx.x;
    const int wave = t >> 6;
    const int lane = t & 63;
    const int row  = blockIdx.x;
    const int e    = (row << 10) + t;               // element index in a plane
    const size_t plane = (size_t)BB * DD;

    // ---- issue ALL 16 scalar loads up-front (16 VGPRs of dests; no pressure) ----
    float M[NN], L[NN];
#pragma unroll
    for (int n = 0; n < NN; ++n) {
        M[n] = means [(size_t)n * plane + e];
        L[n] = logsig[(size_t)n * plane + e];
    }
    // Pin load issue above the scan.
    __builtin_amdgcn_sched_barrier(0);

    // ---- full scan on one element (consumes loads oldest-first) ----
    float m1  = M[0];
    float iv1 = __expf(-L[0]);
    float z   = 0.0f;
#pragma unroll
    for (int n = 1; n < NN; ++n) {
        float v2  = __expf(L[n]);
        float iv2 = __expf(-L[n]);
        float v1  = __builtin_amdgcn_rcpf(iv1);
        float s   = v1 + v2 + 1e-6f;
        float d   = m1 - M[n];
        z += d * d * __builtin_amdgcn_rcpf(s) + __logf(s);
        float ivn = iv1 + iv2;
        float cv  = __builtin_amdgcn_rcpf(ivn);
        m1  = cv * (m1 * iv1 + M[n] * iv2);
        iv1 = ivn;
    }

    // ---- outputs (nontemporal; logvar = -log(iv1)) ----
    __builtin_nontemporal_store(m1,           out_mean   + e);
    __builtin_nontemporal_store(-__logf(iv1), out_logvar + e);

    // ---- z reduction: wave shuffle, then 16-wave LDS combine ----
#pragma unroll
    for (int o = 32; o > 0; o >>= 1)
        z += __shfl_down(z, o, 64);

    __shared__ float sz[16];
    if (lane == 0) sz[wave] = z;
    __syncthreads();
    if (t == 0) {
        float total = 0.0f;
#pragma unroll
        for (int w = 0; w < 16; ++w) total += sz[w];
        out_logz[row] = -0.5f * (total + (float)((NN - 1) * DD) * LOG_2PI);
    }
}

extern "C" void kernel_launch(void* const* d_in, const int* in_sizes, int n_in,
                              void* d_out, int out_size, void* d_ws, size_t ws_size,
                              hipStream_t stream) {
    const float* means  = (const float*)d_in[0];
    const float* logsig = (const float*)d_in[1];
    float* out = (float*)d_out;
    float* out_mean   = out;
    float* out_logvar = out + (size_t)BB * DD;
    float* out_logz   = out + 2 * (size_t)BB * DD;
    mpc_kernel<<<BB, 1024, 0, stream>>>(means, logsig, out_mean, out_logvar, out_logz);
}